// Round 1
// baseline (924.806 us; speedup 1.0000x reference)
//
#include <hip/hip_runtime.h>

// Problem constants (from reference setup_inputs)
constexpr int T = 16;       // tables
constexpr int E = 200000;   // rows per table
constexpr int D = 64;       // embedding dim
constexpr int B = 4096;     // batch
constexpr int L = 20;       // fixed bag length (still read offsets for safety)

// One bag per 16-lane subgroup: lane handles one float4 of the 64-float row.
// Wave = 4 bags -> 64 lanes * 16B = 1 KB per global_load_dwordx4.
// Block 256 threads = 16 bags; grid = T*B/16 = 4096 blocks.
__global__ __launch_bounds__(256) void tbe_pooled_fwd(
    const int*   __restrict__ indices,   // [T*B*L]
    const int*   __restrict__ offsets,   // [T*B+1]
    const float* __restrict__ weights,   // [T, E, D]
    float*       __restrict__ out)       // [B, T*D]
{
    const int tid  = threadIdx.x;
    const int lane = tid & 63;
    const int wave = tid >> 6;
    const int sub  = lane >> 4;          // which of 4 bags in this wave
    const int col  = lane & 15;          // which float4 within the 64-float row

    const int bag = blockIdx.x * 16 + wave * 4 + sub;   // [0, T*B)
    const int t   = bag >> 12;           // bag / B   (B = 4096)
    const int b   = bag & (B - 1);       // bag % B

    const int start = offsets[bag];
    const int end   = offsets[bag + 1];
    const int n     = end - start;

    const float* tbl = weights + (size_t)t * E * D;

    float4 acc = make_float4(0.f, 0.f, 0.f, 0.f);

    if (n == L) {
        // Fast path: fully unrolled -> 20 independent in-flight gathers/lane.
        int idx[L];
#pragma unroll
        for (int l = 0; l < L; ++l) idx[l] = indices[start + l];
#pragma unroll
        for (int l = 0; l < L; ++l) {
            const float4 v = *reinterpret_cast<const float4*>(
                tbl + (size_t)idx[l] * D + col * 4);
            acc.x += v.x; acc.y += v.y; acc.z += v.z; acc.w += v.w;
        }
    } else {
        for (int l = 0; l < n; ++l) {
            const int i = indices[start + l];
            const float4 v = *reinterpret_cast<const float4*>(
                tbl + (size_t)i * D + col * 4);
            acc.x += v.x; acc.y += v.y; acc.z += v.z; acc.w += v.w;
        }
    }

    // out[b, t*D + col*4 .. +3]  -- 256B contiguous per 16-lane subgroup
    float4* outp = reinterpret_cast<float4*>(
        out + (size_t)b * (T * D) + t * D + col * 4);
    *outp = acc;
}

extern "C" void kernel_launch(void* const* d_in, const int* in_sizes, int n_in,
                              void* d_out, int out_size, void* d_ws, size_t ws_size,
                              hipStream_t stream) {
    const int*   indices = (const int*)  d_in[0];
    const int*   offsets = (const int*)  d_in[1];
    const float* weights = (const float*)d_in[2];
    float*       out     = (float*)      d_out;

    const int num_bags = T * B;              // 65536
    const int blocks   = num_bags / 16;      // 4096 blocks * 16 bags/block

    tbe_pooled_fwd<<<blocks, 256, 0, stream>>>(indices, offsets, weights, out);
}